// Round 1
// baseline (452.889 us; speedup 1.0000x reference)
//
#include <hip/hip_runtime.h>

typedef __bf16 bf16;
typedef __bf16 bf16x8 __attribute__((ext_vector_type(8)));
typedef __bf16 bf16x4 __attribute__((ext_vector_type(4)));
typedef float  f32x4  __attribute__((ext_vector_type(4)));

#define NB    128
#define NN    256
#define CC    512
#define OO    256

__device__ __forceinline__ void gl_lds16(const void* g, void* l) {
  __builtin_amdgcn_global_load_lds((const __attribute__((address_space(1))) void*)g,
                                   (__attribute__((address_space(3))) void*)l, 16, 0, 0);
}

__device__ __forceinline__ float sigm_f(float x) {
  x = fminf(fmaxf(x, -30.f), 30.f);
  return 1.f / (1.f + __expf(-x));
}
__device__ __forceinline__ float tanh_f(float x) {
  x = fminf(fmaxf(x, -15.f), 15.f);
  float e = __expf(2.f * x);
  return (e - 1.f) / (e + 1.f);
}

// ---------- elementwise fp32 -> bf16 (x4 vectorized) ----------
__global__ void k_conv(const float* __restrict__ src, bf16* __restrict__ dst, int n4) {
  int stride = gridDim.x * blockDim.x;
  for (int i = blockIdx.x * blockDim.x + threadIdx.x; i < n4; i += stride) {
    float4 v = reinterpret_cast<const float4*>(src)[i];
    bf16x4 o;
    o[0] = (bf16)v.x; o[1] = (bf16)v.y; o[2] = (bf16)v.z; o[3] = (bf16)v.w;
    reinterpret_cast<bf16x4*>(dst)[i] = o;
  }
}

// ---------- tiled transpose: fp32 src[rows][cols] -> bf16 dst[cols][rows], batched on z ----------
__global__ __launch_bounds__(256) void k_tconv(const float* __restrict__ src, bf16* __restrict__ dst,
                                               int rows, int cols) {
  __shared__ bf16 t[64][66];  // pad 2: lane stride 132B = 33 banks -> conflict-free transpose read
  int b = blockIdx.z;
  const float* s = src + (size_t)b * rows * cols;
  bf16* d = dst + (size_t)b * rows * cols;
  int j0 = blockIdx.x * 64, i0 = blockIdx.y * 64;
  int tj = threadIdx.x & 63, t4 = threadIdx.x >> 6;
  #pragma unroll
  for (int p = 0; p < 16; ++p) {
    int i = p * 4 + t4;
    t[i][tj] = (bf16)s[(size_t)(i0 + i) * cols + j0 + tj];
  }
  __syncthreads();
  #pragma unroll
  for (int p = 0; p < 16; ++p) {
    int j = p * 4 + t4;
    d[(size_t)(j0 + j) * rows + i0 + tj] = t[tj][j];
  }
}

// ---------- stage A: msg = adj[b] @ ann[b] + gc_bias, bf16 out ----------
// grid 1024: b=bid>>3, mt=(bid>>2)&1, nt=bid&3. 256 thr, 4 waves (2x2), 128x128 tile, BK=64.
__global__ __launch_bounds__(256) void k_msg(const bf16* __restrict__ adjB,
                                             const bf16* __restrict__ annT,
                                             const float* __restrict__ gcb,
                                             bf16* __restrict__ msgB) {
  __shared__ bf16 As[128 * 64];   // [row][k]
  __shared__ bf16 Bs[128 * 64];   // [n][k]  (from annT, already channel-major)
  int bid = blockIdx.x;
  int b = bid >> 3, mt = (bid >> 2) & 1, nt = bid & 3;
  int tid = threadIdx.x, lane = tid & 63, wid = tid >> 6;
  int wr = wid >> 1, wc = wid & 1;
  f32x4 acc[4][4] = {};
  const bf16* Ab = adjB + (size_t)b * NN * NN + (size_t)mt * 128 * NN;
  const bf16* Bb = annT + (size_t)b * CC * NN + (size_t)nt * 128 * NN;
  for (int kt = 0; kt < NN / 64; ++kt) {
    if (kt) __syncthreads();
    #pragma unroll
    for (int it = 0; it < 4; ++it) {
      int chunk = it * 256 + tid;
      int row = chunk >> 3, cc = chunk & 7;
      gl_lds16(Ab + (size_t)row * NN + kt * 64 + cc * 8, &As[chunk * 8]);
    }
    #pragma unroll
    for (int it = 0; it < 4; ++it) {
      int chunk = it * 256 + tid;
      int row = chunk >> 3, cc = chunk & 7;
      gl_lds16(Bb + (size_t)row * NN + kt * 64 + cc * 8, &Bs[chunk * 8]);
    }
    __syncthreads();
    #pragma unroll
    for (int kk = 0; kk < 2; ++kk) {
      int ko = kk * 32 + 8 * (lane >> 4);
      bf16x8 a[4], bb[4];
      #pragma unroll
      for (int mi = 0; mi < 4; ++mi)
        a[mi] = *(const bf16x8*)&As[(wr * 64 + mi * 16 + (lane & 15)) * 64 + ko];
      #pragma unroll
      for (int ni = 0; ni < 4; ++ni)
        bb[ni] = *(const bf16x8*)&Bs[(wc * 64 + ni * 16 + (lane & 15)) * 64 + ko];
      #pragma unroll
      for (int mi = 0; mi < 4; ++mi)
        #pragma unroll
        for (int ni = 0; ni < 4; ++ni)
          acc[mi][ni] = __builtin_amdgcn_mfma_f32_16x16x32_bf16(a[mi], bb[ni], acc[mi][ni], 0, 0, 0);
    }
  }
  int rg = lane >> 4, cl = lane & 15;
  #pragma unroll
  for (int mi = 0; mi < 4; ++mi)
    #pragma unroll
    for (int ni = 0; ni < 4; ++ni) {
      int c = nt * 128 + wc * 64 + ni * 16 + cl;
      float g = gcb[c];
      #pragma unroll
      for (int r = 0; r < 4; ++r) {
        int R = mt * 128 + wr * 64 + mi * 16 + rg * 4 + r;
        msgB[(size_t)(b * NN + R) * CC + c] = (bf16)(acc[mi][ni][r] + g);
      }
    }
}

// ---------- stage B: fused GRU. grid 2048: mb=bid>>3 (128-row block), cb=bid&7 (64-channel block) ----------
// 512 thr = 8 waves (4x2). Per wave: 32 rows x 32 ch, 6 gate-GEMMs => acc[6][2][2] (96 VGPR).
__global__ __launch_bounds__(512, 2) void k_gru(const bf16* __restrict__ msgB,
                                                const bf16* __restrict__ annB,
                                                const float* __restrict__ annF,
                                                const bf16* __restrict__ Wt,
                                                const bf16* __restrict__ Ut,
                                                const float* __restrict__ grub,
                                                bf16* __restrict__ hnewB) {
  __shared__ bf16 Am[128 * 64];      // msg rows [row][k]
  __shared__ bf16 Ah[128 * 64];      // h rows   [row][k]
  __shared__ bf16 Bw[3 * 64 * 64];   // W panels [gate][n][k] (from Wt, channel-major)
  __shared__ bf16 Bu[3 * 64 * 64];
  int bid = blockIdx.x;
  int cb = bid & 7, mb = bid >> 3;
  int c0 = cb * 64;
  int tid = threadIdx.x, lane = tid & 63, wid = tid >> 6;
  int wr = wid >> 1, wc = wid & 1;
  f32x4 acc[6][2][2] = {};
  for (int kt = 0; kt < CC / 64; ++kt) {
    if (kt) __syncthreads();
    #pragma unroll
    for (int it = 0; it < 2; ++it) {
      int chunk = it * 512 + tid;
      int row = chunk >> 3, cc = chunk & 7;
      size_t goff = (size_t)(mb * 128 + row) * CC + kt * 64 + cc * 8;
      gl_lds16(msgB + goff, &Am[chunk * 8]);
      gl_lds16(annB + goff, &Ah[chunk * 8]);
    }
    #pragma unroll
    for (int it = 0; it < 3; ++it) {
      int chunk = it * 512 + tid;
      int g = chunk >> 9, w = chunk & 511;
      int n = w >> 3, cc = w & 7;
      size_t grow = (size_t)(g * CC + c0 + n) * CC + kt * 64 + cc * 8;
      gl_lds16(Wt + grow, &Bw[chunk * 8]);
      gl_lds16(Ut + grow, &Bu[chunk * 8]);
    }
    __syncthreads();
    #pragma unroll
    for (int kk = 0; kk < 2; ++kk) {
      int ko = kk * 32 + 8 * (lane >> 4);
      bf16x8 am[2], ah[2];
      #pragma unroll
      for (int mi = 0; mi < 2; ++mi) {
        int row = wr * 32 + mi * 16 + (lane & 15);
        am[mi] = *(const bf16x8*)&Am[row * 64 + ko];
        ah[mi] = *(const bf16x8*)&Ah[row * 64 + ko];
      }
      #pragma unroll
      for (int g = 0; g < 3; ++g) {
        bf16x8 bw[2], bu[2];
        #pragma unroll
        for (int ni = 0; ni < 2; ++ni) {
          int n = wc * 32 + ni * 16 + (lane & 15);
          bw[ni] = *(const bf16x8*)&Bw[g * 4096 + n * 64 + ko];
          bu[ni] = *(const bf16x8*)&Bu[g * 4096 + n * 64 + ko];
        }
        #pragma unroll
        for (int mi = 0; mi < 2; ++mi)
          #pragma unroll
          for (int ni = 0; ni < 2; ++ni) {
            acc[g][mi][ni]     = __builtin_amdgcn_mfma_f32_16x16x32_bf16(am[mi], bw[ni], acc[g][mi][ni], 0, 0, 0);
            acc[3 + g][mi][ni] = __builtin_amdgcn_mfma_f32_16x16x32_bf16(ah[mi], bu[ni], acc[3 + g][mi][ni], 0, 0, 0);
          }
      }
    }
  }
  // epilogue: gates + blend, write hnew (bf16)
  int rg = lane >> 4, cl = lane & 15;
  const float* b0 = grub;
  const float* b1 = grub + 3 * CC;
  #pragma unroll
  for (int mi = 0; mi < 2; ++mi)
    #pragma unroll
    for (int ni = 0; ni < 2; ++ni) {
      int c = c0 + wc * 32 + ni * 16 + cl;
      float bz = b0[c] + b1[c];
      float br = b0[CC + c] + b1[CC + c];
      float bh0 = b0[2 * CC + c], bh1 = b1[2 * CC + c];
      #pragma unroll
      for (int r = 0; r < 4; ++r) {
        int R = mb * 128 + wr * 32 + mi * 16 + rg * 4 + r;
        float z  = sigm_f(acc[0][mi][ni][r] + acc[3][mi][ni][r] + bz);
        float rr = sigm_f(acc[1][mi][ni][r] + acc[4][mi][ni][r] + br);
        float hc = tanh_f(acc[2][mi][ni][r] + bh0 + rr * (acc[5][mi][ni][r] + bh1));
        float h  = annF[(size_t)R * CC + c];
        hnewB[(size_t)R * CC + c] = (bf16)(z * h + (1.f - z) * hc);
      }
    }
}

// ---------- stage C: out = hnew @ dense_W + dense_b (fp32 out) ----------
// grid 512: mt=bid>>1 (0..255), nt=bid&1. 128x128 tile.
__global__ __launch_bounds__(256) void k_out(const bf16* __restrict__ hB,
                                             const bf16* __restrict__ DWt,
                                             const float* __restrict__ db,
                                             float* __restrict__ out) {
  __shared__ bf16 As[128 * 64];
  __shared__ bf16 Bs[128 * 64];
  int bid = blockIdx.x;
  int mt = bid >> 1, nt = bid & 1;
  int tid = threadIdx.x, lane = tid & 63, wid = tid >> 6;
  int wr = wid >> 1, wc = wid & 1;
  f32x4 acc[4][4] = {};
  for (int kt = 0; kt < CC / 64; ++kt) {
    if (kt) __syncthreads();
    #pragma unroll
    for (int it = 0; it < 4; ++it) {
      int chunk = it * 256 + tid;
      int row = chunk >> 3, cc = chunk & 7;
      gl_lds16(hB + (size_t)(mt * 128 + row) * CC + kt * 64 + cc * 8, &As[chunk * 8]);
      gl_lds16(DWt + (size_t)(nt * 128 + row) * CC + kt * 64 + cc * 8, &Bs[chunk * 8]);
    }
    __syncthreads();
    #pragma unroll
    for (int kk = 0; kk < 2; ++kk) {
      int ko = kk * 32 + 8 * (lane >> 4);
      bf16x8 a[4], bb[4];
      #pragma unroll
      for (int mi = 0; mi < 4; ++mi)
        a[mi] = *(const bf16x8*)&As[(wr * 64 + mi * 16 + (lane & 15)) * 64 + ko];
      #pragma unroll
      for (int ni = 0; ni < 4; ++ni)
        bb[ni] = *(const bf16x8*)&Bs[(wc * 64 + ni * 16 + (lane & 15)) * 64 + ko];
      #pragma unroll
      for (int mi = 0; mi < 4; ++mi)
        #pragma unroll
        for (int ni = 0; ni < 4; ++ni)
          acc[mi][ni] = __builtin_amdgcn_mfma_f32_16x16x32_bf16(a[mi], bb[ni], acc[mi][ni], 0, 0, 0);
    }
  }
  int rg = lane >> 4, cl = lane & 15;
  #pragma unroll
  for (int mi = 0; mi < 4; ++mi)
    #pragma unroll
    for (int ni = 0; ni < 4; ++ni) {
      int c = nt * 128 + wc * 64 + ni * 16 + cl;
      float g = db[c];
      #pragma unroll
      for (int r = 0; r < 4; ++r) {
        int R = mt * 128 + wr * 64 + mi * 16 + rg * 4 + r;
        out[(size_t)R * OO + c] = acc[mi][ni][r] + g;
      }
    }
}

extern "C" void kernel_launch(void* const* d_in, const int* in_sizes, int n_in,
                              void* d_out, int out_size, void* d_ws, size_t ws_size,
                              hipStream_t stream) {
  const float* adj = (const float*)d_in[0];   // [128,256,256]
  const float* ann = (const float*)d_in[1];   // [128,256,512]
  const float* gcb = (const float*)d_in[2];   // [512]
  const float* gW  = (const float*)d_in[3];   // [512,1536]
  const float* gU  = (const float*)d_in[4];   // [512,1536]
  const float* gb  = (const float*)d_in[5];   // [2,1536]
  const float* dW  = (const float*)d_in[6];   // [512,256]
  const float* db  = (const float*)d_in[7];   // [256]
  float* out = (float*)d_out;                 // [128,256,256] fp32
  char* ws = (char*)d_ws;
  // layout (lifetime-overlapped): hnewB reuses adjB/annT space (dead after k_msg)
  bf16* annB  = (bf16*)(ws + 0);           // 33,554,432 B
  bf16* adjB  = (bf16*)(ws + 33554432);    // 16,777,216 B (dead after k_msg)
  bf16* hnewB = (bf16*)(ws + 33554432);    // 33,554,432 B (written in k_gru)
  bf16* annT  = (bf16*)(ws + 50331648);    // 33,554,432 B (dead after k_msg)
  bf16* msgB  = (bf16*)(ws + 83886080);    // 33,554,432 B
  bf16* WtB   = (bf16*)(ws + 117440512);   //  1,572,864 B
  bf16* UtB   = (bf16*)(ws + 119013376);   //  1,572,864 B
  bf16* DWtB  = (bf16*)(ws + 120586240);   //    262,144 B   -> total ~120.85 MB

  hipLaunchKernelGGL(k_conv, dim3(1024), dim3(256), 0, stream, adj, adjB, 8388608 / 4);
  hipLaunchKernelGGL(k_conv, dim3(2048), dim3(256), 0, stream, ann, annB, 16777216 / 4);
  hipLaunchKernelGGL(k_tconv, dim3(8, 4, 128), dim3(256), 0, stream, ann, annT, 256, 512);
  hipLaunchKernelGGL(k_tconv, dim3(24, 8, 1), dim3(256), 0, stream, gW, WtB, 512, 1536);
  hipLaunchKernelGGL(k_tconv, dim3(24, 8, 1), dim3(256), 0, stream, gU, UtB, 512, 1536);
  hipLaunchKernelGGL(k_tconv, dim3(4, 8, 1), dim3(256), 0, stream, dW, DWtB, 512, 256);
  hipLaunchKernelGGL(k_msg, dim3(1024), dim3(256), 0, stream, adjB, annT, gcb, msgB);
  hipLaunchKernelGGL(k_gru, dim3(2048), dim3(512), 0, stream, msgB, annB, ann, WtB, UtB, gb, hnewB);
  hipLaunchKernelGGL(k_out, dim3(512), dim3(256), 0, stream, hnewB, DWtB, db, out);
}

// Round 2
// 348.174 us; speedup vs baseline: 1.3008x; 1.3008x over previous
//
#include <hip/hip_runtime.h>

typedef __bf16 bf16;
typedef __bf16 bf16x8 __attribute__((ext_vector_type(8)));
typedef __bf16 bf16x4 __attribute__((ext_vector_type(4)));
typedef float  f32x4  __attribute__((ext_vector_type(4)));

#define NB    128
#define NN    256
#define CC    512
#define OO    256

__device__ __forceinline__ void gl_lds16(const void* g, void* l) {
  __builtin_amdgcn_global_load_lds((const __attribute__((address_space(1))) void*)g,
                                   (__attribute__((address_space(3))) void*)l, 16, 0, 0);
}

__device__ __forceinline__ float sigm_f(float x) {
  x = fminf(fmaxf(x, -30.f), 30.f);
  return 1.f / (1.f + __expf(-x));
}
__device__ __forceinline__ float tanh_f(float x) {
  x = fminf(fmaxf(x, -15.f), 15.f);
  float e = __expf(2.f * x);
  return (e - 1.f) / (e + 1.f);
}

// ---------- elementwise fp32 -> bf16 (x4 vectorized) ----------
__global__ void k_conv(const float* __restrict__ src, bf16* __restrict__ dst, int n4) {
  int stride = gridDim.x * blockDim.x;
  for (int i = blockIdx.x * blockDim.x + threadIdx.x; i < n4; i += stride) {
    float4 v = reinterpret_cast<const float4*>(src)[i];
    bf16x4 o;
    o[0] = (bf16)v.x; o[1] = (bf16)v.y; o[2] = (bf16)v.z; o[3] = (bf16)v.w;
    reinterpret_cast<bf16x4*>(dst)[i] = o;
  }
}

// ---------- fused ann prep: fp32 ann -> annB (bf16, same layout) + annT (bf16, [b][C][N]) ----------
__global__ __launch_bounds__(256) void k_annprep(const float* __restrict__ src,
                                                 bf16* __restrict__ dB, bf16* __restrict__ dT) {
  __shared__ bf16 t[64][66];  // pad 2: transpose-read conflict-free
  int b = blockIdx.z;
  const float* s = src + (size_t)b * NN * CC;
  bf16* db_ = dB + (size_t)b * NN * CC;
  bf16* dt_ = dT + (size_t)b * NN * CC;
  int j0 = blockIdx.x * 64, i0 = blockIdx.y * 64;  // j: channel (cols), i: node (rows)
  int tj = threadIdx.x & 63, t4 = threadIdx.x >> 6;
  #pragma unroll
  for (int p = 0; p < 16; ++p) {
    int i = p * 4 + t4;
    bf16 bv = (bf16)s[(size_t)(i0 + i) * CC + j0 + tj];
    t[i][tj] = bv;
    db_[(size_t)(i0 + i) * CC + j0 + tj] = bv;
  }
  __syncthreads();
  #pragma unroll
  for (int p = 0; p < 16; ++p) {
    int j = p * 4 + t4;
    dt_[(size_t)(j0 + j) * NN + i0 + tj] = t[tj][j];
  }
}

// ---------- tiled transpose: fp32 src[rows][cols] -> bf16 dst[cols][rows] ----------
__global__ __launch_bounds__(256) void k_tconv(const float* __restrict__ src, bf16* __restrict__ dst,
                                               int rows, int cols) {
  __shared__ bf16 t[64][66];
  const float* s = src;
  bf16* d = dst;
  int j0 = blockIdx.x * 64, i0 = blockIdx.y * 64;
  int tj = threadIdx.x & 63, t4 = threadIdx.x >> 6;
  #pragma unroll
  for (int p = 0; p < 16; ++p) {
    int i = p * 4 + t4;
    t[i][tj] = (bf16)s[(size_t)(i0 + i) * cols + j0 + tj];
  }
  __syncthreads();
  #pragma unroll
  for (int p = 0; p < 16; ++p) {
    int j = p * 4 + t4;
    d[(size_t)(j0 + j) * rows + i0 + tj] = t[tj][j];
  }
}

// ---------- stage A: msg = adj[b] @ ann[b] + gc_bias, bf16 out ----------
// grid 1024: b=bid>>3, mt=(bid>>2)&1, nt=bid&3. 256 thr, 4 waves (2x2), 128x128 tile, BK=64.
// LDS panels XOR-swizzled: slot (r,c) holds global chunk (r, c^(r&7)); read applies same XOR.
__global__ __launch_bounds__(256) void k_msg(const bf16* __restrict__ adjB,
                                             const bf16* __restrict__ annT,
                                             const float* __restrict__ gcb,
                                             bf16* __restrict__ msgB) {
  __shared__ bf16 As[128 * 64];
  __shared__ bf16 Bs[128 * 64];
  int bid = blockIdx.x;
  int b = bid >> 3, mt = (bid >> 2) & 1, nt = bid & 3;
  int tid = threadIdx.x, lane = tid & 63, wid = tid >> 6;
  int wr = wid >> 1, wc = wid & 1;
  int l15 = lane & 15, ks = lane >> 4;
  f32x4 acc[4][4] = {};
  const bf16* Ab = adjB + (size_t)b * NN * NN + (size_t)mt * 128 * NN;
  const bf16* Bb = annT + (size_t)b * CC * NN + (size_t)nt * 128 * NN;
  for (int kt = 0; kt < NN / 64; ++kt) {
    if (kt) __syncthreads();
    #pragma unroll
    for (int it = 0; it < 4; ++it) {
      int chunk = it * 256 + tid;
      int row = chunk >> 3, cc = chunk & 7;
      int sc = cc ^ (row & 7);
      gl_lds16(Ab + (size_t)row * NN + kt * 64 + sc * 8, &As[chunk * 8]);
    }
    #pragma unroll
    for (int it = 0; it < 4; ++it) {
      int chunk = it * 256 + tid;
      int row = chunk >> 3, cc = chunk & 7;
      int sc = cc ^ (row & 7);
      gl_lds16(Bb + (size_t)row * NN + kt * 64 + sc * 8, &Bs[chunk * 8]);
    }
    __syncthreads();
    #pragma unroll
    for (int kk = 0; kk < 2; ++kk) {
      bf16x8 a[4], bb[4];
      #pragma unroll
      for (int mi = 0; mi < 4; ++mi) {
        int row = wr * 64 + mi * 16 + l15;
        int ch = (kk * 4 + ks) ^ (row & 7);
        a[mi] = *(const bf16x8*)&As[row * 64 + ch * 8];
      }
      #pragma unroll
      for (int ni = 0; ni < 4; ++ni) {
        int n = wc * 64 + ni * 16 + l15;
        int ch = (kk * 4 + ks) ^ (n & 7);
        bb[ni] = *(const bf16x8*)&Bs[n * 64 + ch * 8];
      }
      #pragma unroll
      for (int mi = 0; mi < 4; ++mi)
        #pragma unroll
        for (int ni = 0; ni < 4; ++ni)
          acc[mi][ni] = __builtin_amdgcn_mfma_f32_16x16x32_bf16(a[mi], bb[ni], acc[mi][ni], 0, 0, 0);
    }
  }
  int rg = lane >> 4, cl = lane & 15;
  #pragma unroll
  for (int mi = 0; mi < 4; ++mi)
    #pragma unroll
    for (int ni = 0; ni < 4; ++ni) {
      int c = nt * 128 + wc * 64 + ni * 16 + cl;
      float g = gcb[c];
      #pragma unroll
      for (int r = 0; r < 4; ++r) {
        int R = mt * 128 + wr * 64 + mi * 16 + rg * 4 + r;
        msgB[(size_t)(b * NN + R) * CC + c] = (bf16)(acc[mi][ni][r] + g);
      }
    }
}

// ---------- stage B: fused GRU. grid 2048: mb=bid>>3 (128 rows), cb=bid&7 (64 channels) ----------
// 512 thr = 8 waves (4x2). Wave: 32 rows x 32 ch, 6 gate-GEMMs, acc[6][2][2] (96 VGPR).
// BK=32 (LDS 40KB -> 2 blocks/CU with VGPR cap). Swizzle: slot (r,c) holds chunk (r, c^((r>>1)&3)).
__global__ __launch_bounds__(512, 4) void k_gru(const bf16* __restrict__ msgB,
                                                const bf16* __restrict__ annB,
                                                const float* __restrict__ annF,
                                                const bf16* __restrict__ Wt,
                                                const bf16* __restrict__ Ut,
                                                const float* __restrict__ grub,
                                                bf16* __restrict__ hnewB) {
  __shared__ bf16 Am[128 * 32];      // msg rows [row][k]
  __shared__ bf16 Ah[128 * 32];      // h rows
  __shared__ bf16 Bw[3 * 64 * 32];   // W panels [gate][n][k]
  __shared__ bf16 Bu[3 * 64 * 32];
  int bid = blockIdx.x;
  int cb = bid & 7, mb = bid >> 3;
  int c0 = cb * 64;
  int tid = threadIdx.x, lane = tid & 63, wid = tid >> 6;
  int wr = wid >> 1, wc = wid & 1;
  int l15 = lane & 15, ks = lane >> 4;
  f32x4 acc[6][2][2] = {};
  // staging decode (hoisted): A chunks: 512 = 128 rows x 4; one per thread
  int ar = tid >> 2, ac = tid & 3;
  int asc = ac ^ ((ar >> 1) & 3);
  size_t aoff0 = (size_t)(mb * 128 + ar) * CC + asc * 8;
  // B chunks: 768 per matrix = 3 gates x 64 rows x 4
  int b1nr = tid >> 2, b1c = tid & 3;                  // chunks 0..511
  int b1g = b1nr >> 6, b1n = b1nr & 63;
  int b1sc = b1c ^ ((b1n >> 1) & 3);
  size_t b1off0 = (size_t)(b1g * CC + c0 + b1n) * CC + b1sc * 8;
  int t2 = tid & 255;
  int b2nr = (512 + t2) >> 2, b2c = t2 & 3;            // chunks 512..767 (tid<256)
  int b2g = b2nr >> 6, b2n = b2nr & 63;
  int b2sc = b2c ^ ((b2n >> 1) & 3);
  size_t b2off0 = (size_t)(b2g * CC + c0 + b2n) * CC + b2sc * 8;
  for (int kt = 0; kt < CC / 32; ++kt) {
    if (kt) __syncthreads();
    {
      size_t ko = (size_t)kt * 32;
      gl_lds16(msgB + aoff0 + ko, &Am[tid * 8]);
      gl_lds16(annB + aoff0 + ko, &Ah[tid * 8]);
      gl_lds16(Wt + b1off0 + ko, &Bw[tid * 8]);
      gl_lds16(Ut + b1off0 + ko, &Bu[tid * 8]);
      if (tid < 256) {
        gl_lds16(Wt + b2off0 + ko, &Bw[(512 + t2) * 8]);
        gl_lds16(Ut + b2off0 + ko, &Bu[(512 + t2) * 8]);
      }
    }
    __syncthreads();
    bf16x8 am[2], ah[2];
    #pragma unroll
    for (int mi = 0; mi < 2; ++mi) {
      int row = wr * 32 + mi * 16 + l15;
      int off = row * 32 + ((ks ^ ((row >> 1) & 3)) << 3);
      am[mi] = *(const bf16x8*)&Am[off];
      ah[mi] = *(const bf16x8*)&Ah[off];
    }
    #pragma unroll
    for (int g = 0; g < 3; ++g) {
      bf16x8 bw[2], bu[2];
      #pragma unroll
      for (int ni = 0; ni < 2; ++ni) {
        int n = wc * 32 + ni * 16 + l15;
        int off = g * 2048 + n * 32 + ((ks ^ ((n >> 1) & 3)) << 3);
        bw[ni] = *(const bf16x8*)&Bw[off];
        bu[ni] = *(const bf16x8*)&Bu[off];
      }
      #pragma unroll
      for (int mi = 0; mi < 2; ++mi)
        #pragma unroll
        for (int ni = 0; ni < 2; ++ni) {
          acc[g][mi][ni]     = __builtin_amdgcn_mfma_f32_16x16x32_bf16(am[mi], bw[ni], acc[g][mi][ni], 0, 0, 0);
          acc[3 + g][mi][ni] = __builtin_amdgcn_mfma_f32_16x16x32_bf16(ah[mi], bu[ni], acc[3 + g][mi][ni], 0, 0, 0);
        }
    }
  }
  // epilogue: gates + blend, write hnew (bf16)
  int rg = lane >> 4, cl = lane & 15;
  const float* b0 = grub;
  const float* b1 = grub + 3 * CC;
  #pragma unroll
  for (int mi = 0; mi < 2; ++mi)
    #pragma unroll
    for (int ni = 0; ni < 2; ++ni) {
      int c = c0 + wc * 32 + ni * 16 + cl;
      float bz = b0[c] + b1[c];
      float br = b0[CC + c] + b1[CC + c];
      float bh0 = b0[2 * CC + c], bh1 = b1[2 * CC + c];
      #pragma unroll
      for (int r = 0; r < 4; ++r) {
        int R = mb * 128 + wr * 32 + mi * 16 + rg * 4 + r;
        float z  = sigm_f(acc[0][mi][ni][r] + acc[3][mi][ni][r] + bz);
        float rr = sigm_f(acc[1][mi][ni][r] + acc[4][mi][ni][r] + br);
        float hc = tanh_f(acc[2][mi][ni][r] + bh0 + rr * (acc[5][mi][ni][r] + bh1));
        float h  = annF[(size_t)R * CC + c];
        hnewB[(size_t)R * CC + c] = (bf16)(z * h + (1.f - z) * hc);
      }
    }
}

// ---------- stage C: out = hnew @ dense_W + dense_b (fp32 out) ----------
// grid 512: mt=bid>>1, nt=bid&1. 128x128 tile, BK=64, swizzled.
__global__ __launch_bounds__(256) void k_out(const bf16* __restrict__ hB,
                                             const bf16* __restrict__ DWt,
                                             const float* __restrict__ db,
                                             float* __restrict__ out) {
  __shared__ bf16 As[128 * 64];
  __shared__ bf16 Bs[128 * 64];
  int bid = blockIdx.x;
  int mt = bid >> 1, nt = bid & 1;
  int tid = threadIdx.x, lane = tid & 63, wid = tid >> 6;
  int wr = wid >> 1, wc = wid & 1;
  int l15 = lane & 15, ks = lane >> 4;
  f32x4 acc[4][4] = {};
  for (int kt = 0; kt < CC / 64; ++kt) {
    if (kt) __syncthreads();
    #pragma unroll
    for (int it = 0; it < 4; ++it) {
      int chunk = it * 256 + tid;
      int row = chunk >> 3, cc = chunk & 7;
      int sc = cc ^ (row & 7);
      gl_lds16(hB + (size_t)(mt * 128 + row) * CC + kt * 64 + sc * 8, &As[chunk * 8]);
      gl_lds16(DWt + (size_t)(nt * 128 + row) * CC + kt * 64 + sc * 8, &Bs[chunk * 8]);
    }
    __syncthreads();
    #pragma unroll
    for (int kk = 0; kk < 2; ++kk) {
      bf16x8 a[4], bb[4];
      #pragma unroll
      for (int mi = 0; mi < 4; ++mi) {
        int row = wr * 64 + mi * 16 + l15;
        int ch = (kk * 4 + ks) ^ (row & 7);
        a[mi] = *(const bf16x8*)&As[row * 64 + ch * 8];
      }
      #pragma unroll
      for (int ni = 0; ni < 4; ++ni) {
        int n = wc * 64 + ni * 16 + l15;
        int ch = (kk * 4 + ks) ^ (n & 7);
        bb[ni] = *(const bf16x8*)&Bs[n * 64 + ch * 8];
      }
      #pragma unroll
      for (int mi = 0; mi < 4; ++mi)
        #pragma unroll
        for (int ni = 0; ni < 4; ++ni)
          acc[mi][ni] = __builtin_amdgcn_mfma_f32_16x16x32_bf16(a[mi], bb[ni], acc[mi][ni], 0, 0, 0);
    }
  }
  int rg = lane >> 4, cl = lane & 15;
  #pragma unroll
  for (int mi = 0; mi < 4; ++mi)
    #pragma unroll
    for (int ni = 0; ni < 4; ++ni) {
      int c = nt * 128 + wc * 64 + ni * 16 + cl;
      float g = db[c];
      #pragma unroll
      for (int r = 0; r < 4; ++r) {
        int R = mt * 128 + wr * 64 + mi * 16 + rg * 4 + r;
        out[(size_t)R * OO + c] = acc[mi][ni][r] + g;
      }
    }
}

extern "C" void kernel_launch(void* const* d_in, const int* in_sizes, int n_in,
                              void* d_out, int out_size, void* d_ws, size_t ws_size,
                              hipStream_t stream) {
  const float* adj = (const float*)d_in[0];   // [128,256,256]
  const float* ann = (const float*)d_in[1];   // [128,256,512]
  const float* gcb = (const float*)d_in[2];   // [512]
  const float* gW  = (const float*)d_in[3];   // [512,1536]
  const float* gU  = (const float*)d_in[4];   // [512,1536]
  const float* gb  = (const float*)d_in[5];   // [2,1536]
  const float* dW  = (const float*)d_in[6];   // [512,256]
  const float* db  = (const float*)d_in[7];   // [256]
  float* out = (float*)d_out;                 // [128,256,256] fp32
  char* ws = (char*)d_ws;
  bf16* annB  = (bf16*)(ws + 0);           // 33,554,432 B
  bf16* adjB  = (bf16*)(ws + 33554432);    // 16,777,216 B (dead after k_msg)
  bf16* hnewB = (bf16*)(ws + 33554432);    // 33,554,432 B (written in k_gru)
  bf16* annT  = (bf16*)(ws + 50331648);    // 33,554,432 B (dead after k_msg)
  bf16* msgB  = (bf16*)(ws + 83886080);    // 33,554,432 B
  bf16* WtB   = (bf16*)(ws + 117440512);   //  1,572,864 B
  bf16* UtB   = (bf16*)(ws + 119013376);   //  1,572,864 B
  bf16* DWtB  = (bf16*)(ws + 120586240);   //    262,144 B

  hipLaunchKernelGGL(k_conv, dim3(1024), dim3(256), 0, stream, adj, adjB, 8388608 / 4);
  hipLaunchKernelGGL(k_annprep, dim3(8, 4, 128), dim3(256), 0, stream, ann, annB, annT);
  hipLaunchKernelGGL(k_tconv, dim3(24, 8, 1), dim3(256), 0, stream, gW, WtB, 512, 1536);
  hipLaunchKernelGGL(k_tconv, dim3(24, 8, 1), dim3(256), 0, stream, gU, UtB, 512, 1536);
  hipLaunchKernelGGL(k_tconv, dim3(4, 8, 1), dim3(256), 0, stream, dW, DWtB, 512, 256);
  hipLaunchKernelGGL(k_msg, dim3(1024), dim3(256), 0, stream, adjB, annT, gcb, msgB);
  hipLaunchKernelGGL(k_gru, dim3(2048), dim3(512), 0, stream, msgB, annB, ann, WtB, UtB, gb, hnewB);
  hipLaunchKernelGGL(k_out, dim3(512), dim3(256), 0, stream, hnewB, DWtB, db, out);
}